// Round 9
// baseline (1174.692 us; speedup 1.0000x reference)
//
#include <hip/hip_runtime.h>
#include <math.h>

#define DIM   256
#define KNN   16
#define NPTS  2048
#define NB    8
#define TOTPTS (NB * NPTS)   // 16384
#define RSB   528            // act tile row stride bytes (256*2 + 16B pad)

typedef __attribute__((ext_vector_type(8))) short bf16x8;   // 8 bf16 = 4 VGPR (MFMA A/B frag)
typedef __attribute__((ext_vector_type(4))) float f32x4;    // MFMA C/D frag

__device__ __forceinline__ unsigned short f2b(float f) {
    unsigned u = __builtin_bit_cast(unsigned, f);
    return (unsigned short)((u + 0x7fffu + ((u >> 16) & 1u)) >> 16);   // RNE
}
__device__ __forceinline__ unsigned pack2(float a, float b) {
    return (unsigned)f2b(a) | ((unsigned)f2b(b) << 16);
}

// ws layout (bytes)
#define OFF_KNN 0u
#define OFF_Q   (1u << 20)
#define OFF_K   ((1u << 20) + (16u << 20))
#define OFF_V   ((1u << 20) + (32u << 20))
#define OFF_WB  (49u << 20)                 // 7 bf16 matrices: Wq Wk Wv pm_w2 am_w1 am_w2 Wf
#define OFF_PAR (OFF_WB + 7u * 65536u * 2u) // pm_sc, pm_bo, am_sc, am_bo (4 x 256 f32)

// ------------------------------------------------------------------
// Kernel 0: prep — convert weights fp32->bf16, fuse BN params (validated)
// ------------------------------------------------------------------
__global__ void prep_kernel(const float* __restrict__ Wq, const float* __restrict__ Wk,
                            const float* __restrict__ Wv, const float* __restrict__ pm_w2,
                            const float* __restrict__ am_w1, const float* __restrict__ am_w2,
                            const float* __restrict__ Wf,
                            const float* __restrict__ pm_g1, const float* __restrict__ pm_b1,
                            const float* __restrict__ pm_m1, const float* __restrict__ pm_v1,
                            const float* __restrict__ am_g1, const float* __restrict__ am_b1,
                            const float* __restrict__ am_m1, const float* __restrict__ am_v1,
                            unsigned short* __restrict__ wb,
                            float* __restrict__ pm_sc, float* __restrict__ pm_bo,
                            float* __restrict__ am_sc, float* __restrict__ am_bo) {
    const int tid = blockIdx.x * 256 + threadIdx.x;
    const float* srcs[7] = {Wq, Wk, Wv, pm_w2, am_w1, am_w2, Wf};
    for (int i = tid; i < 7 * 65536; i += gridDim.x * 256) {
        const int m = i >> 16, o = i & 65535;
        wb[i] = f2b(srcs[m][o]);
    }
    if (tid < 256) {
        float s = pm_g1[tid] * rsqrtf(pm_v1[tid] + 1e-5f);
        pm_sc[tid] = s;
        pm_bo[tid] = pm_b1[tid] - pm_m1[tid] * s;
        s = am_g1[tid] * rsqrtf(am_v1[tid] + 1e-5f);
        am_sc[tid] = s;
        am_bo[tid] = am_b1[tid] - am_m1[tid] * s;
    }
}

// ------------------------------------------------------------------
// Kernel 1: kNN — one WAVE per point, no barriers.
// lane holds 32 candidates (m = lane + 64*i) in registers (static idx only).
// 16 rounds: 6-level shfl_xor lex-argmin over (d, m); winner lane rescans.
// Ordering semantics identical to validated block version: lex min (d, m).
// ------------------------------------------------------------------
__global__ __launch_bounds__(256, 8)
void knn_kernel(const float* __restrict__ pos, int* __restrict__ knn_out) {
    const int wid  = (blockIdx.x << 2) | (threadIdx.x >> 6);   // global wave = point
    const int lane = threadIdx.x & 63;
    const int b = wid >> 11;
    const int n = wid & (NPTS - 1);
    const float* __restrict__ posb = pos + (size_t)b * NPTS * 3;

    const float qx = posb[n * 3 + 0], qy = posb[n * 3 + 1], qz = posb[n * 3 + 2];
    const float sqn = __fadd_rn(__fadd_rn(__fmul_rn(qx, qx), __fmul_rn(qy, qy)),
                                __fmul_rn(qz, qz));
    float d[32];
    #pragma unroll
    for (int i = 0; i < 32; ++i) {
        const int m = lane + (i << 6);
        const float mx = posb[m * 3 + 0], my = posb[m * 3 + 1], mz = posb[m * 3 + 2];
        const float sqm = __fadd_rn(__fadd_rn(__fmul_rn(mx, mx), __fmul_rn(my, my)),
                                    __fmul_rn(mz, mz));
        const float dot = __fadd_rn(__fadd_rn(__fmul_rn(qx, mx), __fmul_rn(qy, my)),
                                    __fmul_rn(qz, mz));
        d[i] = __fsub_rn(__fadd_rn(sqn, sqm), __fmul_rn(2.0f, dot));
    }

    // per-lane best over unclaimed slots
    unsigned claimed = 0;
    float bd = d[0];
    int   bm = lane;
    #pragma unroll
    for (int i = 1; i < 32; ++i) {
        const int m = lane + (i << 6);
        if (d[i] < bd || (d[i] == bd && m < bm)) { bd = d[i]; bm = m; }
    }

    int keep = 0;
    for (int r = 0; r < KNN; ++r) {
        float wd = bd;
        int   wm = bm;
        #pragma unroll
        for (int off = 32; off >= 1; off >>= 1) {
            const float od = __shfl_xor(wd, off);
            const int   om = __shfl_xor(wm, off);
            if (od < wd || (od == wd && om < wm)) { wd = od; wm = om; }
        }
        if (lane == r) keep = wm;
        if ((wm & 63) == lane) {          // I own the winning slot: remove + rescan
            claimed |= 1u << (wm >> 6);
            bd = 1e30f; bm = 0x7fffffff;
            #pragma unroll
            for (int i = 0; i < 32; ++i) {
                if (!((claimed >> i) & 1u)) {
                    const int m = lane + (i << 6);
                    if (d[i] < bd || (d[i] == bd && m < bm)) { bd = d[i]; bm = m; }
                }
            }
        }
    }
    if (lane < KNN) knn_out[(size_t)wid * KNN + lane] = keep;
}

// ------------------------------------------------------------------
// MFMA stage (2 col-tiles/wave): acc[rt][ct] += act(64xK LDS) @ Wb^T
// ------------------------------------------------------------------
__device__ __forceinline__ void mfma_stage2(const unsigned char* __restrict__ act,
                                            const unsigned short* __restrict__ Wb,
                                            int qr, int sub, int cbase,
                                            f32x4 acc[4][2]) {
    #pragma unroll
    for (int kk = 0; kk < 8; ++kk) {
        const int kb = kk * 64 + sub * 16;
        bf16x8 afr[4];
        #pragma unroll
        for (int rt = 0; rt < 4; ++rt)
            afr[rt] = *(const bf16x8*)(act + (rt * 16 + qr) * RSB + kb);
        #pragma unroll
        for (int ct = 0; ct < 2; ++ct) {
            const bf16x8 bfr = *(const bf16x8*)(Wb + (size_t)(cbase + ct * 16 + qr) * DIM + kk * 32 + sub * 8);
            #pragma unroll
            for (int rt = 0; rt < 4; ++rt)
                acc[rt][ct] = __builtin_amdgcn_mfma_f32_16x16x32_bf16(afr[rt], bfr,
                                                                      acc[rt][ct], 0, 0, 0);
        }
    }
}

// 4 col-tiles/wave variant (qkv kernel, unchanged semantics — validated)
__device__ __forceinline__ void mfma_stage(const unsigned char* __restrict__ act,
                                           const unsigned short* __restrict__ Wb,
                                           int qr, int sub, int cbase,
                                           f32x4 acc[4][4]) {
    #pragma unroll
    for (int kk = 0; kk < 8; ++kk) {
        const int kb = kk * 64 + sub * 16;
        bf16x8 afr[4], bfr[4];
        #pragma unroll
        for (int rt = 0; rt < 4; ++rt)
            afr[rt] = *(const bf16x8*)(act + (rt * 16 + qr) * RSB + kb);
        #pragma unroll
        for (int ct = 0; ct < 4; ++ct)
            bfr[ct] = *(const bf16x8*)(Wb + (size_t)(cbase + ct * 16 + qr) * DIM + kk * 32 + sub * 8);
        #pragma unroll
        for (int rt = 0; rt < 4; ++rt)
            #pragma unroll
            for (int ct = 0; ct < 4; ++ct)
                acc[rt][ct] = __builtin_amdgcn_mfma_f32_16x16x32_bf16(afr[rt], bfr[ct],
                                                                      acc[rt][ct], 0, 0, 0);
    }
}

// ------------------------------------------------------------------
// Kernel 2: q/k/v projections via MFMA (validated, unchanged)
// ------------------------------------------------------------------
__global__ __launch_bounds__(256, 2)
void qkv_mfma(const float* __restrict__ X, const unsigned short* __restrict__ wb,
              float* __restrict__ Q, float* __restrict__ Kf, float* __restrict__ Vf) {
    __shared__ uint4 act4[64 * RSB / 16];
    unsigned char* act = (unsigned char*)act4;
    const int t = threadIdx.x, lane = t & 63, w = t >> 6;
    const int qr = lane & 15, sub = lane >> 4;
    const int m0 = blockIdx.x * 64;
    const int mat = blockIdx.y;
    const unsigned short* __restrict__ Wb = wb + (size_t)mat * 65536;
    float* __restrict__ O = (mat == 0) ? Q : (mat == 1) ? Kf : Vf;

    {
        const int r = t >> 2;
        const float* __restrict__ src = X + (size_t)(m0 + r) * DIM;
        #pragma unroll
        for (int j = 0; j < 8; ++j) {
            const int col = (t & 3) * 8 + j * 32;
            const float4 f0 = *(const float4*)(src + col);
            const float4 f1 = *(const float4*)(src + col + 4);
            uint4 u;
            u.x = pack2(f0.x, f0.y); u.y = pack2(f0.z, f0.w);
            u.z = pack2(f1.x, f1.y); u.w = pack2(f1.z, f1.w);
            *(uint4*)(act + r * RSB + col * 2) = u;
        }
    }
    __syncthreads();

    f32x4 acc[4][4];
    #pragma unroll
    for (int rt = 0; rt < 4; ++rt)
        #pragma unroll
        for (int ct = 0; ct < 4; ++ct) acc[rt][ct] = (f32x4)(0.0f);

    mfma_stage(act, Wb, qr, sub, w * 64, acc);

    #pragma unroll
    for (int rt = 0; rt < 4; ++rt)
        #pragma unroll
        for (int ct = 0; ct < 4; ++ct) {
            const int c = w * 64 + ct * 16 + qr;
            #pragma unroll
            for (int reg = 0; reg < 4; ++reg)
                O[(size_t)(m0 + rt * 16 + sub * 4 + reg) * DIM + c] = acc[rt][ct][reg];
        }
}

// ------------------------------------------------------------------
// Kernel 3: fused per-point transformer.
// 512 thr = 8 waves; block = 4 points (64-row M-tile); wave owns 32 cols
// (ct in {0,1}) -> halved accumulators, target <=128 VGPR, 4 waves/SIMD.
// ------------------------------------------------------------------
__global__ __launch_bounds__(512, 4)
void fused_attn(const float* __restrict__ x, const float* __restrict__ pos,
                const int* __restrict__ knn,
                const float* __restrict__ qf, const float* __restrict__ kf,
                const float* __restrict__ vf,
                const unsigned short* __restrict__ wb,
                const float* __restrict__ pm_w1,
                const float* __restrict__ pm_sc, const float* __restrict__ pm_bo,
                const float* __restrict__ am_sc, const float* __restrict__ am_bo,
                const float* __restrict__ bfin,
                float* __restrict__ out) {
    __shared__ uint4 act4[64 * RSB / 16];     // 33792 B
    __shared__ int   nb_lds[64];
    __shared__ float4 rel_lds[64];
    unsigned char* act = (unsigned char*)act4;

    const int t = threadIdx.x, lane = t & 63, w = t >> 6;   // w: 0..7
    const int qr = lane & 15, sub = lane >> 4;
    const int pt_base = blockIdx.x << 2;
    const int bbase = pt_base & ~(NPTS - 1);
    const int cbase = w * 32;

    // neighbor idx + rel staging (threads 0..63)
    if (t < 64) {
        const int pi = t >> 4;
        const int j = knn[(size_t)(pt_base + pi) * KNN + (t & 15)];
        nb_lds[t] = j;
        const float* __restrict__ pp = pos + (size_t)(pt_base + pi) * 3;
        const float* __restrict__ pj = pos + (size_t)(bbase + j) * 3;
        rel_lds[t] = make_float4(pp[0] - pj[0], pp[1] - pj[1], pp[2] - pj[2], 0.0f);
    }
    __syncthreads();

    // ---- stage 1: pe1 = relu(bn(rel @ pm_w1^T)) -> act LDS (bf16)
    // thread: col (t&255), row-half (t>>8)
    {
        const int c  = t & 255;
        const int rh = t >> 8;            // 0 or 1
        const float w0 = pm_w1[c * 3 + 0], w1 = pm_w1[c * 3 + 1], w2 = pm_w1[c * 3 + 2];
        const float sc = pm_sc[c], bo = pm_bo[c];
        #pragma unroll
        for (int rr = 0; rr < 32; ++rr) {
            const int r = rh * 32 + rr;
            const float4 rl = rel_lds[r];
            float h = fmaf(rl.z, w2, fmaf(rl.y, w1, rl.x * w0));
            h = fmaxf(fmaf(h, sc, bo), 0.0f);
            *(unsigned short*)(act + r * RSB + c * 2) = f2b(h);
        }
    }
    __syncthreads();

    // ---- stage 2: pe = pe1 @ pm_w2^T -> peacc (fp32, kept to the end)
    f32x4 peacc[4][2];
    #pragma unroll
    for (int rt = 0; rt < 4; ++rt)
        #pragma unroll
        for (int ct = 0; ct < 2; ++ct) peacc[rt][ct] = (f32x4)(0.0f);
    mfma_stage2(act, wb + 3u * 65536u, qr, sub, cbase, peacc);
    __syncthreads();   // pe1 reads done

    // this lane's neighbor indices: rows sub*4+reg of each point rt
    int nbr[4][4];
    #pragma unroll
    for (int rt = 0; rt < 4; ++rt)
        #pragma unroll
        for (int reg = 0; reg < 4; ++reg)
            nbr[rt][reg] = nb_lds[rt * 16 + sub * 4 + reg];

    // ---- stage 3: a0 = q - k_gather + pe -> act LDS (bf16)
    #pragma unroll
    for (int rt = 0; rt < 4; ++rt)
        #pragma unroll
        for (int ct = 0; ct < 2; ++ct) {
            const int c = cbase + ct * 16 + qr;
            const float qv = qf[(size_t)(pt_base + rt) * DIM + c];
            #pragma unroll
            for (int reg = 0; reg < 4; ++reg) {
                const float kv = kf[(size_t)(bbase + nbr[rt][reg]) * DIM + c];
                const float a0 = qv - kv + peacc[rt][ct][reg];
                *(unsigned short*)(act + (rt * 16 + sub * 4 + reg) * RSB + c * 2) = f2b(a0);
            }
        }
    __syncthreads();

    // ---- stage 4: a1 = relu(bn(a0 @ am_w1^T))
    f32x4 acc2[4][2];
    #pragma unroll
    for (int rt = 0; rt < 4; ++rt)
        #pragma unroll
        for (int ct = 0; ct < 2; ++ct) acc2[rt][ct] = (f32x4)(0.0f);
    mfma_stage2(act, wb + 4u * 65536u, qr, sub, cbase, acc2);
    __syncthreads();   // a0 reads done
    #pragma unroll
    for (int ct = 0; ct < 2; ++ct) {
        const int c = cbase + ct * 16 + qr;
        const float sc = am_sc[c], bo = am_bo[c];
        #pragma unroll
        for (int rt = 0; rt < 4; ++rt)
            #pragma unroll
            for (int reg = 0; reg < 4; ++reg) {
                const float h = fmaxf(fmaf(acc2[rt][ct][reg], sc, bo), 0.0f);
                *(unsigned short*)(act + (rt * 16 + sub * 4 + reg) * RSB + c * 2) = f2b(h);
            }
    }
    __syncthreads();

    // ---- stage 5: a2 = a1 @ am_w2^T
    #pragma unroll
    for (int rt = 0; rt < 4; ++rt)
        #pragma unroll
        for (int ct = 0; ct < 2; ++ct) acc2[rt][ct] = (f32x4)(0.0f);
    mfma_stage2(act, wb + 5u * 65536u, qr, sub, cbase, acc2);

    // ---- stage 6: softmax over the 16 neighbors (reg x sub)
    #pragma unroll
    for (int rt = 0; rt < 4; ++rt)
        #pragma unroll
        for (int ct = 0; ct < 2; ++ct) {
            float m = -1e30f;
            #pragma unroll
            for (int reg = 0; reg < 4; ++reg) {
                acc2[rt][ct][reg] *= 0.0625f;   // / sqrt(256)
                m = fmaxf(m, acc2[rt][ct][reg]);
            }
            m = fmaxf(m, __shfl_xor(m, 16));
            m = fmaxf(m, __shfl_xor(m, 32));
            float s = 0.0f;
            #pragma unroll
            for (int reg = 0; reg < 4; ++reg) {
                const float e = __expf(acc2[rt][ct][reg] - m);
                acc2[rt][ct][reg] = e;
                s += e;
            }
            s += __shfl_xor(s, 16);
            s += __shfl_xor(s, 32);
            const float inv = 1.0f / s;
            #pragma unroll
            for (int reg = 0; reg < 4; ++reg) acc2[rt][ct][reg] *= inv;
        }

    // ---- stage 7: agg = sum_k attn * (v_gather + pe)
    float agg[4][2];
    #pragma unroll
    for (int rt = 0; rt < 4; ++rt)
        #pragma unroll
        for (int ct = 0; ct < 2; ++ct) {
            const int c = cbase + ct * 16 + qr;
            float p = 0.0f;
            #pragma unroll
            for (int reg = 0; reg < 4; ++reg) {
                const float vv = vf[(size_t)(bbase + nbr[rt][reg]) * DIM + c];
                p = fmaf(acc2[rt][ct][reg], vv + peacc[rt][ct][reg], p);
            }
            p += __shfl_xor(p, 16);
            p += __shfl_xor(p, 32);
            agg[rt][ct] = p;
        }
    __syncthreads();   // all act (a1) reads done block-wide; safe to overwrite

    // ---- stage 8: final linear via MFMA on a 16x256 A-tile (rows 0-3 = points)
    {
        unsigned* actw = (unsigned*)act;
        for (int i = t; i < 12 * (RSB / 4); i += 512) actw[4 * (RSB / 4) + i] = 0;  // rows 4..15
        if (sub == 0) {
            #pragma unroll
            for (int rt = 0; rt < 4; ++rt)
                #pragma unroll
                for (int ct = 0; ct < 2; ++ct) {
                    const int c = cbase + ct * 16 + qr;
                    *(unsigned short*)(act + rt * RSB + c * 2) = f2b(agg[rt][ct]);
                }
        }
    }
    __syncthreads();

    f32x4 facc[2];
    facc[0] = (f32x4)(0.0f);
    facc[1] = (f32x4)(0.0f);
    const unsigned short* __restrict__ Wfb = wb + 6u * 65536u;
    #pragma unroll
    for (int kk = 0; kk < 8; ++kk) {
        const int kb = kk * 64 + sub * 16;
        const bf16x8 af = *(const bf16x8*)(act + qr * RSB + kb);
        #pragma unroll
        for (int ct = 0; ct < 2; ++ct) {
            const bf16x8 bfr = *(const bf16x8*)(Wfb + (size_t)(cbase + ct * 16 + qr) * DIM + kk * 32 + sub * 8);
            facc[ct] = __builtin_amdgcn_mfma_f32_16x16x32_bf16(af, bfr, facc[ct], 0, 0, 0);
        }
    }
    if (sub == 0) {
        #pragma unroll
        for (int ct = 0; ct < 2; ++ct) {
            const int c = cbase + ct * 16 + qr;
            #pragma unroll
            for (int reg = 0; reg < 4; ++reg) {
                const size_t row = (size_t)(pt_base + reg) * DIM + c;
                out[row] = facc[ct][reg] + bfin[c] + x[row];
            }
        }
    }
}

// ------------------------------------------------------------------
extern "C" void kernel_launch(void* const* d_in, const int* in_sizes, int n_in,
                              void* d_out, int out_size, void* d_ws, size_t ws_size,
                              hipStream_t stream) {
    const float* x     = (const float*)d_in[0];
    const float* pos   = (const float*)d_in[1];
    const float* Wq    = (const float*)d_in[2];
    const float* Wk    = (const float*)d_in[3];
    const float* Wv    = (const float*)d_in[4];
    const float* pm_w1 = (const float*)d_in[5];
    const float* pm_g1 = (const float*)d_in[6];
    const float* pm_b1 = (const float*)d_in[7];
    const float* pm_m1 = (const float*)d_in[8];
    const float* pm_v1 = (const float*)d_in[9];
    const float* pm_w2 = (const float*)d_in[10];
    const float* am_w1 = (const float*)d_in[11];
    const float* am_g1 = (const float*)d_in[12];
    const float* am_b1 = (const float*)d_in[13];
    const float* am_m1 = (const float*)d_in[14];
    const float* am_v1 = (const float*)d_in[15];
    const float* am_w2 = (const float*)d_in[16];
    const float* Wf    = (const float*)d_in[17];
    const float* bfin  = (const float*)d_in[18];
    float* out = (float*)d_out;

    char* ws = (char*)d_ws;
    int*            knn_idx = (int*)(ws + OFF_KNN);
    float*          qf = (float*)(ws + OFF_Q);
    float*          kf = (float*)(ws + OFF_K);
    float*          vf = (float*)(ws + OFF_V);
    unsigned short* wb = (unsigned short*)(ws + OFF_WB);
    float*          pm_sc = (float*)(ws + OFF_PAR);
    float*          pm_bo = pm_sc + 256;
    float*          am_sc = pm_sc + 512;
    float*          am_bo = pm_sc + 768;

    prep_kernel<<<448, 256, 0, stream>>>(Wq, Wk, Wv, pm_w2, am_w1, am_w2, Wf,
                                         pm_g1, pm_b1, pm_m1, pm_v1,
                                         am_g1, am_b1, am_m1, am_v1,
                                         wb, pm_sc, pm_bo, am_sc, am_bo);
    knn_kernel<<<TOTPTS / 4, 256, 0, stream>>>(pos, knn_idx);
    qkv_mfma<<<dim3(TOTPTS / 64, 3), 256, 0, stream>>>(x, wb, qf, kf, vf);
    fused_attn<<<TOTPTS / 4, 512, 0, stream>>>(x, pos, knn_idx, qf, kf, vf, wb,
                                               pm_w1, pm_sc, pm_bo, am_sc, am_bo,
                                               bfin, out);
}

// Round 13
// 613.111 us; speedup vs baseline: 1.9160x; 1.9160x over previous
//
#include <hip/hip_runtime.h>
#include <math.h>

#define DIM   256
#define KNN   16
#define NPTS  2048
#define NB    8
#define TOTPTS (NB * NPTS)   // 16384
#define RSB   528            // act tile row stride bytes (256*2 + 16B pad)

typedef __attribute__((ext_vector_type(8))) short bf16x8;   // 8 bf16 = 4 VGPR (MFMA A/B frag)
typedef __attribute__((ext_vector_type(4))) float f32x4;    // MFMA C/D frag

__device__ __forceinline__ unsigned short f2b(float f) {
    unsigned u = __builtin_bit_cast(unsigned, f);
    return (unsigned short)((u + 0x7fffu + ((u >> 16) & 1u)) >> 16);   // RNE
}
__device__ __forceinline__ unsigned pack2(float a, float b) {
    return (unsigned)f2b(a) | ((unsigned)f2b(b) << 16);
}

// ws layout (bytes)
#define OFF_KNN 0u
#define OFF_Q   (1u << 20)
#define OFF_K   ((1u << 20) + (16u << 20))
#define OFF_V   ((1u << 20) + (32u << 20))
#define OFF_WB  (49u << 20)                 // 7 bf16 matrices: Wq Wk Wv pm_w2 am_w1 am_w2 Wf
#define OFF_PAR (OFF_WB + 7u * 65536u * 2u) // pm_sc, pm_bo, am_sc, am_bo (4 x 256 f32)

// ------------------------------------------------------------------
// Kernel 0: prep — convert weights fp32->bf16, fuse BN params (validated)
// ------------------------------------------------------------------
__global__ void prep_kernel(const float* __restrict__ Wq, const float* __restrict__ Wk,
                            const float* __restrict__ Wv, const float* __restrict__ pm_w2,
                            const float* __restrict__ am_w1, const float* __restrict__ am_w2,
                            const float* __restrict__ Wf,
                            const float* __restrict__ pm_g1, const float* __restrict__ pm_b1,
                            const float* __restrict__ pm_m1, const float* __restrict__ pm_v1,
                            const float* __restrict__ am_g1, const float* __restrict__ am_b1,
                            const float* __restrict__ am_m1, const float* __restrict__ am_v1,
                            unsigned short* __restrict__ wb,
                            float* __restrict__ pm_sc, float* __restrict__ pm_bo,
                            float* __restrict__ am_sc, float* __restrict__ am_bo) {
    const int tid = blockIdx.x * 256 + threadIdx.x;
    const float* srcs[7] = {Wq, Wk, Wv, pm_w2, am_w1, am_w2, Wf};
    for (int i = tid; i < 7 * 65536; i += gridDim.x * 256) {
        const int m = i >> 16, o = i & 65535;
        wb[i] = f2b(srcs[m][o]);
    }
    if (tid < 256) {
        float s = pm_g1[tid] * rsqrtf(pm_v1[tid] + 1e-5f);
        pm_sc[tid] = s;
        pm_bo[tid] = pm_b1[tid] - pm_m1[tid] * s;
        s = am_g1[tid] * rsqrtf(am_v1[tid] + 1e-5f);
        am_sc[tid] = s;
        am_bo[tid] = am_b1[tid] - am_m1[tid] * s;
    }
}

// ------------------------------------------------------------------
// Kernel 1: kNN — one WAVE per point, no barriers in the selection.
// FIX vs round-9: (a) launch_bounds (256,4) so d[32] stays in registers
// (was (256,8) -> 64-VGPR cap -> 1.2 GB scratch spill traffic);
// (b) batch positions staged once per block in LDS (24 KB), stride-3
// float reads are bank-conflict-free (3 coprime 32).
// Selection logic byte-identical to the validated round-9 version.
// ------------------------------------------------------------------
__global__ __launch_bounds__(256, 4)
void knn_kernel(const float* __restrict__ pos, int* __restrict__ knn_out) {
    __shared__ float sp[NPTS * 3];            // 24 KB: batch positions, interleaved
    const int wv   = threadIdx.x >> 6;
    const int lane = threadIdx.x & 63;
    const int wid  = (blockIdx.x << 2) | wv;  // global wave = point
    const int b = wid >> 11;
    const int n = wid & (NPTS - 1);
    const float* __restrict__ posb = pos + (size_t)b * NPTS * 3;

    // cooperative stage: 6144 floats = 1536 float4, 256 threads x 6
    {
        const float4* __restrict__ src4 = (const float4*)posb;
        float4* dst4 = (float4*)sp;
        #pragma unroll
        for (int i = 0; i < 6; ++i)
            dst4[threadIdx.x + i * 256] = src4[threadIdx.x + i * 256];
    }
    __syncthreads();

    const float qx = sp[n * 3 + 0], qy = sp[n * 3 + 1], qz = sp[n * 3 + 2];
    const float sqn = __fadd_rn(__fadd_rn(__fmul_rn(qx, qx), __fmul_rn(qy, qy)),
                                __fmul_rn(qz, qz));
    float d[32];
    #pragma unroll
    for (int i = 0; i < 32; ++i) {
        const int m = lane + (i << 6);
        const float mx = sp[m * 3 + 0], my = sp[m * 3 + 1], mz = sp[m * 3 + 2];
        const float sqm = __fadd_rn(__fadd_rn(__fmul_rn(mx, mx), __fmul_rn(my, my)),
                                    __fmul_rn(mz, mz));
        const float dot = __fadd_rn(__fadd_rn(__fmul_rn(qx, mx), __fmul_rn(qy, my)),
                                    __fmul_rn(qz, mz));
        d[i] = __fsub_rn(__fadd_rn(sqn, sqm), __fmul_rn(2.0f, dot));
    }

    // per-lane best over unclaimed slots
    unsigned claimed = 0;
    float bd = d[0];
    int   bm = lane;
    #pragma unroll
    for (int i = 1; i < 32; ++i) {
        const int m = lane + (i << 6);
        if (d[i] < bd || (d[i] == bd && m < bm)) { bd = d[i]; bm = m; }
    }

    int keep = 0;
    for (int r = 0; r < KNN; ++r) {
        float wd = bd;
        int   wm = bm;
        #pragma unroll
        for (int off = 32; off >= 1; off >>= 1) {
            const float od = __shfl_xor(wd, off);
            const int   om = __shfl_xor(wm, off);
            if (od < wd || (od == wd && om < wm)) { wd = od; wm = om; }
        }
        if (lane == r) keep = wm;
        if ((wm & 63) == lane) {          // I own the winning slot: remove + rescan
            claimed |= 1u << (wm >> 6);
            bd = 1e30f; bm = 0x7fffffff;
            #pragma unroll
            for (int i = 0; i < 32; ++i) {
                if (!((claimed >> i) & 1u)) {
                    const int m = lane + (i << 6);
                    if (d[i] < bd || (d[i] == bd && m < bm)) { bd = d[i]; bm = m; }
                }
            }
        }
    }
    if (lane < KNN) knn_out[(size_t)wid * KNN + lane] = keep;
}

// ------------------------------------------------------------------
// MFMA stage (2 col-tiles/wave): acc[rt][ct] += act(64xK LDS) @ Wb^T
// ------------------------------------------------------------------
__device__ __forceinline__ void mfma_stage2(const unsigned char* __restrict__ act,
                                            const unsigned short* __restrict__ Wb,
                                            int qr, int sub, int cbase,
                                            f32x4 acc[4][2]) {
    #pragma unroll
    for (int kk = 0; kk < 8; ++kk) {
        const int kb = kk * 64 + sub * 16;
        bf16x8 afr[4];
        #pragma unroll
        for (int rt = 0; rt < 4; ++rt)
            afr[rt] = *(const bf16x8*)(act + (rt * 16 + qr) * RSB + kb);
        #pragma unroll
        for (int ct = 0; ct < 2; ++ct) {
            const bf16x8 bfr = *(const bf16x8*)(Wb + (size_t)(cbase + ct * 16 + qr) * DIM + kk * 32 + sub * 8);
            #pragma unroll
            for (int rt = 0; rt < 4; ++rt)
                acc[rt][ct] = __builtin_amdgcn_mfma_f32_16x16x32_bf16(afr[rt], bfr,
                                                                      acc[rt][ct], 0, 0, 0);
        }
    }
}

// 4 col-tiles/wave variant (qkv kernel, unchanged semantics — validated)
__device__ __forceinline__ void mfma_stage(const unsigned char* __restrict__ act,
                                           const unsigned short* __restrict__ Wb,
                                           int qr, int sub, int cbase,
                                           f32x4 acc[4][4]) {
    #pragma unroll
    for (int kk = 0; kk < 8; ++kk) {
        const int kb = kk * 64 + sub * 16;
        bf16x8 afr[4], bfr[4];
        #pragma unroll
        for (int rt = 0; rt < 4; ++rt)
            afr[rt] = *(const bf16x8*)(act + (rt * 16 + qr) * RSB + kb);
        #pragma unroll
        for (int ct = 0; ct < 4; ++ct)
            bfr[ct] = *(const bf16x8*)(Wb + (size_t)(cbase + ct * 16 + qr) * DIM + kk * 32 + sub * 8);
        #pragma unroll
        for (int rt = 0; rt < 4; ++rt)
            #pragma unroll
            for (int ct = 0; ct < 4; ++ct)
                acc[rt][ct] = __builtin_amdgcn_mfma_f32_16x16x32_bf16(afr[rt], bfr[ct],
                                                                      acc[rt][ct], 0, 0, 0);
    }
}

// ------------------------------------------------------------------
// Kernel 2: q/k/v projections via MFMA (validated, unchanged)
// ------------------------------------------------------------------
__global__ __launch_bounds__(256, 2)
void qkv_mfma(const float* __restrict__ X, const unsigned short* __restrict__ wb,
              float* __restrict__ Q, float* __restrict__ Kf, float* __restrict__ Vf) {
    __shared__ uint4 act4[64 * RSB / 16];
    unsigned char* act = (unsigned char*)act4;
    const int t = threadIdx.x, lane = t & 63, w = t >> 6;
    const int qr = lane & 15, sub = lane >> 4;
    const int m0 = blockIdx.x * 64;
    const int mat = blockIdx.y;
    const unsigned short* __restrict__ Wb = wb + (size_t)mat * 65536;
    float* __restrict__ O = (mat == 0) ? Q : (mat == 1) ? Kf : Vf;

    {
        const int r = t >> 2;
        const float* __restrict__ src = X + (size_t)(m0 + r) * DIM;
        #pragma unroll
        for (int j = 0; j < 8; ++j) {
            const int col = (t & 3) * 8 + j * 32;
            const float4 f0 = *(const float4*)(src + col);
            const float4 f1 = *(const float4*)(src + col + 4);
            uint4 u;
            u.x = pack2(f0.x, f0.y); u.y = pack2(f0.z, f0.w);
            u.z = pack2(f1.x, f1.y); u.w = pack2(f1.z, f1.w);
            *(uint4*)(act + r * RSB + col * 2) = u;
        }
    }
    __syncthreads();

    f32x4 acc[4][4];
    #pragma unroll
    for (int rt = 0; rt < 4; ++rt)
        #pragma unroll
        for (int ct = 0; ct < 4; ++ct) acc[rt][ct] = (f32x4)(0.0f);

    mfma_stage(act, Wb, qr, sub, w * 64, acc);

    #pragma unroll
    for (int rt = 0; rt < 4; ++rt)
        #pragma unroll
        for (int ct = 0; ct < 4; ++ct) {
            const int c = w * 64 + ct * 16 + qr;
            #pragma unroll
            for (int reg = 0; reg < 4; ++reg)
                O[(size_t)(m0 + rt * 16 + sub * 4 + reg) * DIM + c] = acc[rt][ct][reg];
        }
}

// ------------------------------------------------------------------
// Kernel 3: fused per-point transformer (unchanged from round 6/9).
// 512 thr = 8 waves; block = 4 points (64-row M-tile); wave owns 32 cols.
// ------------------------------------------------------------------
__global__ __launch_bounds__(512, 4)
void fused_attn(const float* __restrict__ x, const float* __restrict__ pos,
                const int* __restrict__ knn,
                const float* __restrict__ qf, const float* __restrict__ kf,
                const float* __restrict__ vf,
                const unsigned short* __restrict__ wb,
                const float* __restrict__ pm_w1,
                const float* __restrict__ pm_sc, const float* __restrict__ pm_bo,
                const float* __restrict__ am_sc, const float* __restrict__ am_bo,
                const float* __restrict__ bfin,
                float* __restrict__ out) {
    __shared__ uint4 act4[64 * RSB / 16];     // 33792 B
    __shared__ int   nb_lds[64];
    __shared__ float4 rel_lds[64];
    unsigned char* act = (unsigned char*)act4;

    const int t = threadIdx.x, lane = t & 63, w = t >> 6;   // w: 0..7
    const int qr = lane & 15, sub = lane >> 4;
    const int pt_base = blockIdx.x << 2;
    const int bbase = pt_base & ~(NPTS - 1);
    const int cbase = w * 32;

    // neighbor idx + rel staging (threads 0..63)
    if (t < 64) {
        const int pi = t >> 4;
        const int j = knn[(size_t)(pt_base + pi) * KNN + (t & 15)];
        nb_lds[t] = j;
        const float* __restrict__ pp = pos + (size_t)(pt_base + pi) * 3;
        const float* __restrict__ pj = pos + (size_t)(bbase + j) * 3;
        rel_lds[t] = make_float4(pp[0] - pj[0], pp[1] - pj[1], pp[2] - pj[2], 0.0f);
    }
    __syncthreads();

    // ---- stage 1: pe1 = relu(bn(rel @ pm_w1^T)) -> act LDS (bf16)
    {
        const int c  = t & 255;
        const int rh = t >> 8;            // 0 or 1
        const float w0 = pm_w1[c * 3 + 0], w1 = pm_w1[c * 3 + 1], w2 = pm_w1[c * 3 + 2];
        const float sc = pm_sc[c], bo = pm_bo[c];
        #pragma unroll
        for (int rr = 0; rr < 32; ++rr) {
            const int r = rh * 32 + rr;
            const float4 rl = rel_lds[r];
            float h = fmaf(rl.z, w2, fmaf(rl.y, w1, rl.x * w0));
            h = fmaxf(fmaf(h, sc, bo), 0.0f);
            *(unsigned short*)(act + r * RSB + c * 2) = f2b(h);
        }
    }
    __syncthreads();

    // ---- stage 2: pe = pe1 @ pm_w2^T -> peacc (fp32, kept to the end)
    f32x4 peacc[4][2];
    #pragma unroll
    for (int rt = 0; rt < 4; ++rt)
        #pragma unroll
        for (int ct = 0; ct < 2; ++ct) peacc[rt][ct] = (f32x4)(0.0f);
    mfma_stage2(act, wb + 3u * 65536u, qr, sub, cbase, peacc);
    __syncthreads();   // pe1 reads done

    // this lane's neighbor indices: rows sub*4+reg of each point rt
    int nbr[4][4];
    #pragma unroll
    for (int rt = 0; rt < 4; ++rt)
        #pragma unroll
        for (int reg = 0; reg < 4; ++reg)
            nbr[rt][reg] = nb_lds[rt * 16 + sub * 4 + reg];

    // ---- stage 3: a0 = q - k_gather + pe -> act LDS (bf16)
    #pragma unroll
    for (int rt = 0; rt < 4; ++rt)
        #pragma unroll
        for (int ct = 0; ct < 2; ++ct) {
            const int c = cbase + ct * 16 + qr;
            const float qv = qf[(size_t)(pt_base + rt) * DIM + c];
            #pragma unroll
            for (int reg = 0; reg < 4; ++reg) {
                const float kv = kf[(size_t)(bbase + nbr[rt][reg]) * DIM + c];
                const float a0 = qv - kv + peacc[rt][ct][reg];
                *(unsigned short*)(act + (rt * 16 + sub * 4 + reg) * RSB + c * 2) = f2b(a0);
            }
        }
    __syncthreads();

    // ---- stage 4: a1 = relu(bn(a0 @ am_w1^T))
    f32x4 acc2[4][2];
    #pragma unroll
    for (int rt = 0; rt < 4; ++rt)
        #pragma unroll
        for (int ct = 0; ct < 2; ++ct) acc2[rt][ct] = (f32x4)(0.0f);
    mfma_stage2(act, wb + 4u * 65536u, qr, sub, cbase, acc2);
    __syncthreads();   // a0 reads done
    #pragma unroll
    for (int ct = 0; ct < 2; ++ct) {
        const int c = cbase + ct * 16 + qr;
        const float sc = am_sc[c], bo = am_bo[c];
        #pragma unroll
        for (int rt = 0; rt < 4; ++rt)
            #pragma unroll
            for (int reg = 0; reg < 4; ++reg) {
                const float h = fmaxf(fmaf(acc2[rt][ct][reg], sc, bo), 0.0f);
                *(unsigned short*)(act + (rt * 16 + sub * 4 + reg) * RSB + c * 2) = f2b(h);
            }
    }
    __syncthreads();

    // ---- stage 5: a2 = a1 @ am_w2^T
    #pragma unroll
    for (int rt = 0; rt < 4; ++rt)
        #pragma unroll
        for (int ct = 0; ct < 2; ++ct) acc2[rt][ct] = (f32x4)(0.0f);
    mfma_stage2(act, wb + 5u * 65536u, qr, sub, cbase, acc2);

    // ---- stage 6: softmax over the 16 neighbors (reg x sub)
    #pragma unroll
    for (int rt = 0; rt < 4; ++rt)
        #pragma unroll
        for (int ct = 0; ct < 2; ++ct) {
            float m = -1e30f;
            #pragma unroll
            for (int reg = 0; reg < 4; ++reg) {
                acc2[rt][ct][reg] *= 0.0625f;   // / sqrt(256)
                m = fmaxf(m, acc2[rt][ct][reg]);
            }
            m = fmaxf(m, __shfl_xor(m, 16));
            m = fmaxf(m, __shfl_xor(m, 32));
            float s = 0.0f;
            #pragma unroll
            for (int reg = 0; reg < 4; ++reg) {
                const float e = __expf(acc2[rt][ct][reg] - m);
                acc2[rt][ct][reg] = e;
                s += e;
            }
            s += __shfl_xor(s, 16);
            s += __shfl_xor(s, 32);
            const float inv = 1.0f / s;
            #pragma unroll
            for (int reg = 0; reg < 4; ++reg) acc2[rt][ct][reg] *= inv;
        }

    // ---- stage 7: agg = sum_k attn * (v_gather + pe)
    float agg[4][2];
    #pragma unroll
    for (int rt = 0; rt < 4; ++rt)
        #pragma unroll
        for (int ct = 0; ct < 2; ++ct) {
            const int c = cbase + ct * 16 + qr;
            float p = 0.0f;
            #pragma unroll
            for (int reg = 0; reg < 4; ++reg) {
                const float vv = vf[(size_t)(bbase + nbr[rt][reg]) * DIM + c];
                p = fmaf(acc2[rt][ct][reg], vv + peacc[rt][ct][reg], p);
            }
            p += __shfl_xor(p, 16);
            p += __shfl_xor(p, 32);
            agg[rt][ct] = p;
        }
    __syncthreads();   // all act (a1) reads done block-wide; safe to overwrite

    // ---- stage 8: final linear via MFMA on a 16x256 A-tile (rows 0-3 = points)
    {
        unsigned* actw = (unsigned*)act;
        for (int i = t; i < 12 * (RSB / 4); i += 512) actw[4 * (RSB / 4) + i] = 0;  // rows 4..15
        if (sub == 0) {
            #pragma unroll
            for (int rt = 0; rt < 4; ++rt)
                #pragma unroll
                for (int ct = 0; ct < 2; ++ct) {
                    const int c = cbase + ct * 16 + qr;
                    *(unsigned short*)(act + rt * RSB + c * 2) = f2b(agg[rt][ct]);
                }
        }
    }
    __syncthreads();

    f32x4 facc[2];
    facc[0] = (f32x4)(0.0f);
    facc[1] = (f32x4)(0.0f);
    const unsigned short* __restrict__ Wfb = wb + 6u * 65536u;
    #pragma unroll
    for (int kk = 0; kk < 8; ++kk) {
        const int kb = kk * 64 + sub * 16;
        const bf16x8 af = *(const bf16x8*)(act + qr * RSB + kb);
        #pragma unroll
        for (int ct = 0; ct < 2; ++ct) {
            const bf16x8 bfr = *(const bf16x8*)(Wfb + (size_t)(cbase + ct * 16 + qr) * DIM + kk * 32 + sub * 8);
            facc[ct] = __builtin_amdgcn_mfma_f32_16x16x32_bf16(af, bfr, facc[ct], 0, 0, 0);
        }
    }
    if (sub == 0) {
        #pragma unroll
        for (int ct = 0; ct < 2; ++ct) {
            const int c = cbase + ct * 16 + qr;
            #pragma unroll
            for (int reg = 0; reg < 4; ++reg) {
                const size_t row = (size_t)(pt_base + reg) * DIM + c;
                out[row] = facc[ct][reg] + bfin[c] + x[row];
            }
        }
    }
}

// ------------------------------------------------------------------
extern "C" void kernel_launch(void* const* d_in, const int* in_sizes, int n_in,
                              void* d_out, int out_size, void* d_ws, size_t ws_size,
                              hipStream_t stream) {
    const float* x     = (const float*)d_in[0];
    const float* pos   = (const float*)d_in[1];
    const float* Wq    = (const float*)d_in[2];
    const float* Wk    = (const float*)d_in[3];
    const float* Wv    = (const float*)d_in[4];
    const float* pm_w1 = (const float*)d_in[5];
    const float* pm_g1 = (const float*)d_in[6];
    const float* pm_b1 = (const float*)d_in[7];
    const float* pm_m1 = (const float*)d_in[8];
    const float* pm_v1 = (const float*)d_in[9];
    const float* pm_w2 = (const float*)d_in[10];
    const float* am_w1 = (const float*)d_in[11];
    const float* am_g1 = (const float*)d_in[12];
    const float* am_b1 = (const float*)d_in[13];
    const float* am_m1 = (const float*)d_in[14];
    const float* am_v1 = (const float*)d_in[15];
    const float* am_w2 = (const float*)d_in[16];
    const float* Wf    = (const float*)d_in[17];
    const float* bfin  = (const float*)d_in[18];
    float* out = (float*)d_out;

    char* ws = (char*)d_ws;
    int*            knn_idx = (int*)(ws + OFF_KNN);
    float*          qf = (float*)(ws + OFF_Q);
    float*          kf = (float*)(ws + OFF_K);
    float*          vf = (float*)(ws + OFF_V);
    unsigned short* wb = (unsigned short*)(ws + OFF_WB);
    float*          pm_sc = (float*)(ws + OFF_PAR);
    float*          pm_bo = pm_sc + 256;
    float*          am_sc = pm_sc + 512;
    float*          am_bo = pm_sc + 768;

    prep_kernel<<<448, 256, 0, stream>>>(Wq, Wk, Wv, pm_w2, am_w1, am_w2, Wf,
                                         pm_g1, pm_b1, pm_m1, pm_v1,
                                         am_g1, am_b1, am_m1, am_v1,
                                         wb, pm_sc, pm_bo, am_sc, am_bo);
    knn_kernel<<<TOTPTS / 4, 256, 0, stream>>>(pos, knn_idx);
    qkv_mfma<<<dim3(TOTPTS / 64, 3), 256, 0, stream>>>(x, wb, qf, kf, vf);
    fused_attn<<<TOTPTS / 4, 512, 0, stream>>>(x, pos, knn_idx, qf, kf, vf, wb,
                                               pm_w1, pm_sc, pm_bo, am_sc, am_bo,
                                               bfin, out);
}